// Round 1
// baseline (680.577 us; speedup 1.0000x reference)
//
#include <hip/hip_runtime.h>
#include <hip/hip_bf16.h>
#include <math.h>

#define T_TOKENS 8192
#define HID 1024
#define FFN 2048
#define NEXP 16
#define TWOF 4096
#define NPAIR (2*T_TOKENS)
#define TM 64
#define MAXTILES 272

typedef short bf16x8 __attribute__((ext_vector_type(8)));
typedef float f32x4 __attribute__((ext_vector_type(4)));

// ---- workspace layout (bytes) ----
// h bf16 [NPAIR][FFN], then int arrays
static const size_t H_OFF    = 0;
static const size_t H_BYTES  = (size_t)NPAIR * FFN * 2;      // 64 MB
static const size_t WTK_OFF  = H_BYTES;                      // float[NPAIR]
static const size_t ETK_OFF  = WTK_OFF  + (size_t)NPAIR*4;   // int[NPAIR]
static const size_t RANK_OFF = ETK_OFF  + (size_t)NPAIR*4;   // int[NPAIR]
static const size_t LIST_OFF = RANK_OFF + (size_t)NPAIR*4;   // int[NPAIR]
static const size_t CNT_OFF  = LIST_OFF + (size_t)NPAIR*4;   // int[16]
static const size_t OFFS_OFF = CNT_OFF  + 64;                // int[17]
static const size_t TEXP_OFF = OFFS_OFF + 128;               // int[MAXTILES]
static const size_t TSEG_OFF = TEXP_OFF + (size_t)MAXTILES*4;
static const size_t HDR_OFF  = TSEG_OFF + (size_t)MAXTILES*4; // int[1]

__device__ inline unsigned short f2bf(float f) {
  union { float f; unsigned u; } v; v.f = f;
  unsigned r = v.u + 0x7fff + ((v.u >> 16) & 1);
  return (unsigned short)(r >> 16);
}

__device__ inline bf16x8 pack8(float4 a, float4 b) {
  bf16x8 r;
  r[0]=(short)f2bf(a.x); r[1]=(short)f2bf(a.y); r[2]=(short)f2bf(a.z); r[3]=(short)f2bf(a.w);
  r[4]=(short)f2bf(b.x); r[5]=(short)f2bf(b.y); r[6]=(short)f2bf(b.z); r[7]=(short)f2bf(b.w);
  return r;
}

// ---- kernel 1: router logits (fp32 exact), one wave per token ----
__global__ __launch_bounds__(256) void k_logits(const float* __restrict__ x,
                                                const float* __restrict__ gw,
                                                float* __restrict__ logits) {
  int tid = threadIdx.x;
  int wave = tid >> 6, lane = tid & 63;
  int t = blockIdx.x * 4 + wave;
  const float* xp = x + (size_t)t * HID;
  float acc[NEXP];
  #pragma unroll
  for (int e = 0; e < NEXP; e++) acc[e] = 0.f;
  for (int i = lane; i < HID; i += 64) {
    float xv = xp[i];
    #pragma unroll
    for (int e = 0; e < NEXP; e++) acc[e] += xv * gw[e*HID + i];
  }
  float mine = 0.f;
  #pragma unroll
  for (int e = 0; e < NEXP; e++) {
    float v = acc[e];
    #pragma unroll
    for (int o = 32; o > 0; o >>= 1) v += __shfl_xor(v, o, 64);
    if (lane == e) mine = v;
  }
  if (lane < NEXP) logits[(size_t)t*NEXP + lane] = mine;
}

// ---- kernel 2a: exact sparsemixer per token + atomic ranks ----
__global__ __launch_bounds__(256) void k_route(const float* __restrict__ logits,
                                               float* __restrict__ wtk, int* __restrict__ etk,
                                               int* __restrict__ rank, int* __restrict__ counts) {
  int t = blockIdx.x*256 + threadIdx.x;
  if (t >= T_TOKENS) return;
  float s[NEXP];
  const float* lp = logits + (size_t)t*NEXP;
  #pragma unroll
  for (int e = 0; e < NEXP; e++) s[e] = lp[e];

  float m1 = s[0]; int i1 = 0;
  #pragma unroll
  for (int e = 1; e < NEXP; e++) if (s[e] > m1) { m1 = s[e]; i1 = e; }
  float sum1 = 0.f;
  #pragma unroll
  for (int e = 0; e < NEXP; e++) {
    float f = fmaxf(fabsf(s[e]), m1);
    if (!((m1 - s[e]) > 0.02f*f)) sum1 += expf(s[e]-m1);
  }
  float m2 = -INFINITY; int i2 = 0;
  #pragma unroll
  for (int e = 0; e < NEXP; e++) if (e != i1 && s[e] > m2) { m2 = s[e]; i2 = e; }
  float sum2 = 0.f;
  #pragma unroll
  for (int e = 0; e < NEXP; e++) {
    if (e == i1) continue;
    float f = fmaxf(fabsf(s[e]), m2);
    if (!((m2 - s[e]) > 0.02f*f)) sum2 += expf(s[e]-m2);
  }
  wtk[t*2]   = 1.f/sum1;
  wtk[t*2+1] = 1.f/sum2;
  etk[t*2]   = i1;
  etk[t*2+1] = i2;
  rank[t*2]   = atomicAdd(&counts[i1], 1);
  rank[t*2+1] = atomicAdd(&counts[i2], 1);
}

// ---- kernel 2b: scan + tile map (single thread; trivial) ----
__global__ void k_scan(const int* __restrict__ counts, int* __restrict__ offsets,
                       int* __restrict__ texp, int* __restrict__ tseg, int* __restrict__ hdr) {
  if (threadIdx.x != 0 || blockIdx.x != 0) return;
  int off = 0, nt = 0;
  for (int e = 0; e < NEXP; e++) {
    offsets[e] = off;
    int c = counts[e];
    int tiles = (c + TM - 1)/TM;
    for (int i = 0; i < tiles; i++) { texp[nt] = e; tseg[nt] = i; nt++; }
    off += c;
  }
  offsets[NEXP] = off;
  hdr[0] = nt;
}

// ---- kernel 2c: scatter pair ids into grouped list ----
__global__ __launch_bounds__(256) void k_scatter(const int* __restrict__ etk,
                                                 const int* __restrict__ rank,
                                                 const int* __restrict__ offsets,
                                                 int* __restrict__ list) {
  int p = blockIdx.x*256 + threadIdx.x;
  if (p >= NPAIR) return;
  int e = etk[p];
  list[offsets[e] + rank[p]] = p;
}

// ---- kernel 3: grouped gate_up GEMM + silu*up*w -> h (bf16) ----
__global__ __launch_bounds__(256) void k_gateup(const float* __restrict__ x,
                                                const float* __restrict__ gup,
                                                const float* __restrict__ wtk,
                                                const int* __restrict__ list,
                                                const int* __restrict__ counts,
                                                const int* __restrict__ offsets,
                                                const int* __restrict__ texp,
                                                const int* __restrict__ tseg,
                                                const int* __restrict__ hdr,
                                                unsigned short* __restrict__ hbuf) {
  int by = blockIdx.y;
  if (by >= hdr[0]) return;
  int e = texp[by];
  int m0 = tseg[by]*TM;
  int seg0 = offsets[e];
  int cnt = counts[e];
  int rows = min(TM, cnt - m0);
  int fofs = blockIdx.x * 64;

  __shared__ __align__(16) unsigned short Al[TM][32];
  __shared__ __align__(16) unsigned short B1[64][32];
  __shared__ __align__(16) unsigned short B3[64][32];

  int tid = threadIdx.x;
  int r = tid >> 2;
  int c8 = (tid & 3) * 8;
  int pr = min(m0 + r, cnt - 1);
  int tok = list[seg0 + pr] >> 1;
  const float* xp = x + (size_t)tok*HID + c8;
  const float* g1 = gup + ((size_t)e*TWOF + fofs + r)*HID + c8;
  const float* g3 = gup + ((size_t)e*TWOF + FFN + fofs + r)*HID + c8;

  int wid = tid >> 6, lane = tid & 63;
  int wr = wid >> 1, wc = wid & 1;
  int lrow = lane & 15, lk = (lane >> 4) * 8;

  f32x4 accg[2][2] = {};
  f32x4 accu[2][2] = {};

  for (int k0 = 0; k0 < HID; k0 += 32) {
    float4 a0 = *(const float4*)(xp + k0);
    float4 a1 = *(const float4*)(xp + k0 + 4);
    float4 b0 = *(const float4*)(g1 + k0);
    float4 b1v = *(const float4*)(g1 + k0 + 4);
    float4 c0 = *(const float4*)(g3 + k0);
    float4 c1 = *(const float4*)(g3 + k0 + 4);
    __syncthreads();
    *(bf16x8*)&Al[r][c8] = pack8(a0, a1);
    *(bf16x8*)&B1[r][c8] = pack8(b0, b1v);
    *(bf16x8*)&B3[r][c8] = pack8(c0, c1);
    __syncthreads();
    bf16x8 af[2], bg[2], bu[2];
    #pragma unroll
    for (int sm = 0; sm < 2; sm++) af[sm] = *(const bf16x8*)&Al[wr*32 + sm*16 + lrow][lk];
    #pragma unroll
    for (int sn = 0; sn < 2; sn++) {
      bg[sn] = *(const bf16x8*)&B1[wc*32 + sn*16 + lrow][lk];
      bu[sn] = *(const bf16x8*)&B3[wc*32 + sn*16 + lrow][lk];
    }
    #pragma unroll
    for (int sm = 0; sm < 2; sm++)
      #pragma unroll
      for (int sn = 0; sn < 2; sn++) {
        accg[sm][sn] = __builtin_amdgcn_mfma_f32_16x16x32_bf16(af[sm], bg[sn], accg[sm][sn], 0, 0, 0);
        accu[sm][sn] = __builtin_amdgcn_mfma_f32_16x16x32_bf16(af[sm], bu[sn], accu[sm][sn], 0, 0, 0);
      }
  }

  // epilogue: h = silu(g)*u*w, store bf16
  #pragma unroll
  for (int sm = 0; sm < 2; sm++) {
    #pragma unroll
    for (int j = 0; j < 4; j++) {
      int row = wr*32 + sm*16 + (lane >> 4)*4 + j;
      if (row < rows) {
        int slot = seg0 + m0 + row;
        float w = wtk[list[slot]];
        #pragma unroll
        for (int sn = 0; sn < 2; sn++) {
          int col = fofs + wc*32 + sn*16 + lrow;
          float g = accg[sm][sn][j];
          float u = accu[sm][sn][j];
          float hv = g / (1.f + __expf(-g)) * u * w;
          hbuf[(size_t)slot*FFN + col] = f2bf(hv);
        }
      }
    }
  }
}

// ---- kernel 4: grouped down GEMM + scatter-add into out ----
__global__ __launch_bounds__(256) void k_down(const unsigned short* __restrict__ hbuf,
                                              const float* __restrict__ dw,
                                              const int* __restrict__ list,
                                              const int* __restrict__ counts,
                                              const int* __restrict__ offsets,
                                              const int* __restrict__ texp,
                                              const int* __restrict__ tseg,
                                              const int* __restrict__ hdr,
                                              float* __restrict__ out) {
  int by = blockIdx.y;
  if (by >= hdr[0]) return;
  int e = texp[by];
  int m0 = tseg[by]*TM;
  int seg0 = offsets[e];
  int cnt = counts[e];
  int rows = min(TM, cnt - m0);
  int nofs = blockIdx.x * 64;

  __shared__ __align__(16) unsigned short Al[TM][32];
  __shared__ __align__(16) unsigned short Bl[64][32];

  int tid = threadIdx.x;
  int r = tid >> 2;
  int c8 = (tid & 3) * 8;
  int pr = min(m0 + r, cnt - 1);
  const unsigned short* ap = hbuf + (size_t)(seg0 + pr)*FFN + c8;
  const float* bp = dw + ((size_t)e*HID + nofs + r)*FFN + c8;

  int wid = tid >> 6, lane = tid & 63;
  int wr = wid >> 1, wc = wid & 1;
  int lrow = lane & 15, lk = (lane >> 4) * 8;

  f32x4 acc[2][2] = {};

  for (int k0 = 0; k0 < FFN; k0 += 32) {
    bf16x8 av = *(const bf16x8*)(ap + k0);
    float4 b0 = *(const float4*)(bp + k0);
    float4 b1v = *(const float4*)(bp + k0 + 4);
    __syncthreads();
    *(bf16x8*)&Al[r][c8] = av;
    *(bf16x8*)&Bl[r][c8] = pack8(b0, b1v);
    __syncthreads();
    bf16x8 af[2], bfm[2];
    #pragma unroll
    for (int sm = 0; sm < 2; sm++) af[sm] = *(const bf16x8*)&Al[wr*32 + sm*16 + lrow][lk];
    #pragma unroll
    for (int sn = 0; sn < 2; sn++) bfm[sn] = *(const bf16x8*)&Bl[wc*32 + sn*16 + lrow][lk];
    #pragma unroll
    for (int sm = 0; sm < 2; sm++)
      #pragma unroll
      for (int sn = 0; sn < 2; sn++)
        acc[sm][sn] = __builtin_amdgcn_mfma_f32_16x16x32_bf16(af[sm], bfm[sn], acc[sm][sn], 0, 0, 0);
  }

  #pragma unroll
  for (int sm = 0; sm < 2; sm++) {
    #pragma unroll
    for (int j = 0; j < 4; j++) {
      int row = wr*32 + sm*16 + (lane >> 4)*4 + j;
      if (row < rows) {
        int t = list[seg0 + m0 + row] >> 1;
        #pragma unroll
        for (int sn = 0; sn < 2; sn++) {
          int col = nofs + wc*32 + sn*16 + lrow;
          unsafeAtomicAdd(&out[(size_t)t*HID + col], acc[sm][sn][j]);
        }
      }
    }
  }
}

extern "C" void kernel_launch(void* const* d_in, const int* in_sizes, int n_in,
                              void* d_out, int out_size, void* d_ws, size_t ws_size,
                              hipStream_t stream) {
  const float* x   = (const float*)d_in[0];
  const float* gw  = (const float*)d_in[1];
  const float* gup = (const float*)d_in[2];
  const float* dwn = (const float*)d_in[3];

  float* out = (float*)d_out;
  float* logits = out + (size_t)T_TOKENS*HID;

  char* ws = (char*)d_ws;
  unsigned short* hbuf = (unsigned short*)(ws + H_OFF);
  float* wtk   = (float*)(ws + WTK_OFF);
  int* etk     = (int*)(ws + ETK_OFF);
  int* rank    = (int*)(ws + RANK_OFF);
  int* list    = (int*)(ws + LIST_OFF);
  int* counts  = (int*)(ws + CNT_OFF);
  int* offsets = (int*)(ws + OFFS_OFF);
  int* texp    = (int*)(ws + TEXP_OFF);
  int* tseg    = (int*)(ws + TSEG_OFF);
  int* hdr     = (int*)(ws + HDR_OFF);

  hipMemsetAsync(out, 0, (size_t)T_TOKENS*HID*4, stream);
  hipMemsetAsync(counts, 0, 64, stream);

  k_logits<<<T_TOKENS/4, 256, 0, stream>>>(x, gw, logits);
  k_route<<<T_TOKENS/256, 256, 0, stream>>>(logits, wtk, etk, rank, counts);
  k_scan<<<1, 64, 0, stream>>>(counts, offsets, texp, tseg, hdr);
  k_scatter<<<NPAIR/256, 256, 0, stream>>>(etk, rank, offsets, list);

  dim3 g3(FFN/64, MAXTILES);
  k_gateup<<<g3, 256, 0, stream>>>(x, gup, wtk, list, counts, offsets, texp, tseg, hdr, hbuf);

  dim3 g4(HID/64, MAXTILES);
  k_down<<<g4, 256, 0, stream>>>(hbuf, dwn, list, counts, offsets, texp, tseg, hdr, out);
}

// Round 2
// 632.802 us; speedup vs baseline: 1.0755x; 1.0755x over previous
//
#include <hip/hip_runtime.h>
#include <hip/hip_bf16.h>
#include <math.h>

#define T_TOKENS 8192
#define HID 1024
#define FFN 2048
#define NEXP 16
#define NPAIR (2*T_TOKENS)
#define TM 128
#define MAXTILES 144

typedef short bf16x8 __attribute__((ext_vector_type(8)));
typedef float f32x4 __attribute__((ext_vector_type(4)));

// ---- workspace layout (bytes) ----
static const size_t HPACK_OFF = 0;                                   // h packed tiles [MAXTILES][32][16KB]
static const size_t HPACK_SZ  = (size_t)MAXTILES * 32 * 16384;       // 75,497,472
static const size_t GPACK_OFF = HPACK_OFF + HPACK_SZ;                // gup bf16 tiles [16][64][16][8KB]
static const size_t GPACK_SZ  = (size_t)16 * 64 * 16 * 8192;         // 134,217,728
static const size_t DPACK_OFF = GPACK_OFF + GPACK_SZ;                // down bf16 tiles [16][16][32][8KB]
static const size_t DPACK_SZ  = (size_t)16 * 16 * 32 * 8192;         // 67,108,864
static const size_t XBF_OFF   = DPACK_OFF + DPACK_SZ;                // x bf16 [T][H]
static const size_t XBF_SZ    = (size_t)T_TOKENS * HID * 2;          // 16,777,216
static const size_t WTK_OFF   = XBF_OFF + XBF_SZ;                    // float[NPAIR]
static const size_t ETK_OFF   = WTK_OFF  + (size_t)NPAIR*4;
static const size_t RANK_OFF  = ETK_OFF  + (size_t)NPAIR*4;
static const size_t LIST_OFF  = RANK_OFF + (size_t)NPAIR*4;
static const size_t CNT_OFF   = LIST_OFF + (size_t)NPAIR*4;
static const size_t OFFS_OFF  = CNT_OFF  + 64;
static const size_t TEXP_OFF  = OFFS_OFF + 128;
static const size_t TSEG_OFF  = TEXP_OFF + (size_t)MAXTILES*4;
static const size_t HDR_OFF   = TSEG_OFF + (size_t)MAXTILES*4;

__device__ __forceinline__ unsigned short f2bf(float f) {
  union { float f; unsigned u; } v; v.f = f;
  unsigned r = v.u + 0x7fff + ((v.u >> 16) & 1);
  return (unsigned short)(r >> 16);
}

__device__ __forceinline__ bf16x8 pack8(float4 a, float4 b) {
  bf16x8 r;
  r[0]=(short)f2bf(a.x); r[1]=(short)f2bf(a.y); r[2]=(short)f2bf(a.z); r[3]=(short)f2bf(a.w);
  r[4]=(short)f2bf(b.x); r[5]=(short)f2bf(b.y); r[6]=(short)f2bf(b.z); r[7]=(short)f2bf(b.w);
  return r;
}

// async global->LDS, 16B per lane. Global src is PER-LANE, LDS dest is wave-uniform base (+lane*16 by HW).
__device__ __forceinline__ void ld16(const unsigned short* g, unsigned short* l) {
  __builtin_amdgcn_global_load_lds((const __attribute__((address_space(1))) void*)g,
                                   (__attribute__((address_space(3))) void*)l, 16, 0, 0);
}

// ---- x fp32 -> bf16 ----
__global__ __launch_bounds__(256) void k_xbf(const float* __restrict__ x, unsigned short* __restrict__ xbf) {
  int i = (blockIdx.x*256 + threadIdx.x) * 8;
  float4 a = *(const float4*)(x + i);
  float4 b = *(const float4*)(x + i + 4);
  *(bf16x8*)(xbf + i) = pack8(a, b);
}

// ---- weight pack: fp32 [E][nbcnt*64][kdim] -> bf16 fragment-major 8KB tiles ----
// tile (e, nb, kb): entry idx = (klocal>>3)*64 + n   (n = output col 0..63), 8 elems each
__global__ __launch_bounds__(256) void k_pack(const float* __restrict__ src, unsigned short* __restrict__ dst,
                                              int nbcnt, int kbcnt, int kdim) {
  int e = blockIdx.z, nb = blockIdx.y, kb = blockIdx.x;
  __shared__ unsigned short tile[4096]; // 8KB
  int tid = threadIdx.x;
  int n = tid >> 2, ks = (tid & 3) * 16;
  const float* s = src + ((size_t)((e*nbcnt + nb)*64 + n))*kdim + kb*64 + ks;
  float4 f0 = *(const float4*)(s);
  float4 f1 = *(const float4*)(s + 4);
  float4 f2 = *(const float4*)(s + 8);
  float4 f3 = *(const float4*)(s + 12);
  int kkc0 = ks >> 3;
  *(bf16x8*)&tile[(kkc0*64 + n)*8]     = pack8(f0, f1);
  *(bf16x8*)&tile[((kkc0+1)*64 + n)*8] = pack8(f2, f3);
  __syncthreads();
  unsigned short* d = dst + ((size_t)(e*nbcnt + nb)*kbcnt + kb)*4096 + tid*16;
  *(bf16x8*)(d)     = *(const bf16x8*)&tile[tid*16];
  *(bf16x8*)(d + 8) = *(const bf16x8*)&tile[tid*16 + 8];
}

// ---- router logits (fp32 exact), one wave per token ----
__global__ __launch_bounds__(256) void k_logits(const float* __restrict__ x,
                                                const float* __restrict__ gw,
                                                float* __restrict__ logits) {
  int tid = threadIdx.x;
  int wave = tid >> 6, lane = tid & 63;
  int t = blockIdx.x * 4 + wave;
  const float* xp = x + (size_t)t * HID;
  float acc[NEXP];
  #pragma unroll
  for (int e = 0; e < NEXP; e++) acc[e] = 0.f;
  for (int i = lane; i < HID; i += 64) {
    float xv = xp[i];
    #pragma unroll
    for (int e = 0; e < NEXP; e++) acc[e] += xv * gw[e*HID + i];
  }
  float mine = 0.f;
  #pragma unroll
  for (int e = 0; e < NEXP; e++) {
    float v = acc[e];
    #pragma unroll
    for (int o = 32; o > 0; o >>= 1) v += __shfl_xor(v, o, 64);
    if (lane == e) mine = v;
  }
  if (lane < NEXP) logits[(size_t)t*NEXP + lane] = mine;
}

// ---- exact sparsemixer per token + atomic ranks ----
__global__ __launch_bounds__(256) void k_route(const float* __restrict__ logits,
                                               float* __restrict__ wtk, int* __restrict__ etk,
                                               int* __restrict__ rank, int* __restrict__ counts) {
  int t = blockIdx.x*256 + threadIdx.x;
  if (t >= T_TOKENS) return;
  float s[NEXP];
  const float* lp = logits + (size_t)t*NEXP;
  #pragma unroll
  for (int e = 0; e < NEXP; e++) s[e] = lp[e];

  float m1 = s[0]; int i1 = 0;
  #pragma unroll
  for (int e = 1; e < NEXP; e++) if (s[e] > m1) { m1 = s[e]; i1 = e; }
  float sum1 = 0.f;
  #pragma unroll
  for (int e = 0; e < NEXP; e++) {
    float f = fmaxf(fabsf(s[e]), m1);
    if (!((m1 - s[e]) > 0.02f*f)) sum1 += expf(s[e]-m1);
  }
  float m2 = -INFINITY; int i2 = 0;
  #pragma unroll
  for (int e = 0; e < NEXP; e++) if (e != i1 && s[e] > m2) { m2 = s[e]; i2 = e; }
  float sum2 = 0.f;
  #pragma unroll
  for (int e = 0; e < NEXP; e++) {
    if (e == i1) continue;
    float f = fmaxf(fabsf(s[e]), m2);
    if (!((m2 - s[e]) > 0.02f*f)) sum2 += expf(s[e]-m2);
  }
  wtk[t*2]   = 1.f/sum1;
  wtk[t*2+1] = 1.f/sum2;
  etk[t*2]   = i1;
  etk[t*2+1] = i2;
  rank[t*2]   = atomicAdd(&counts[i1], 1);
  rank[t*2+1] = atomicAdd(&counts[i2], 1);
}

// ---- scan + tile map ----
__global__ void k_scan(const int* __restrict__ counts, int* __restrict__ offsets,
                       int* __restrict__ texp, int* __restrict__ tseg, int* __restrict__ hdr) {
  if (threadIdx.x != 0 || blockIdx.x != 0) return;
  int off = 0, nt = 0;
  for (int e = 0; e < NEXP; e++) {
    offsets[e] = off;
    int c = counts[e];
    int tiles = (c + TM - 1)/TM;
    for (int i = 0; i < tiles; i++) { texp[nt] = e; tseg[nt] = i; nt++; }
    off += c;
  }
  offsets[NEXP] = off;
  hdr[0] = nt;
}

// ---- scatter pair ids into grouped list ----
__global__ __launch_bounds__(256) void k_scatter(const int* __restrict__ etk,
                                                 const int* __restrict__ rank,
                                                 const int* __restrict__ offsets,
                                                 int* __restrict__ list) {
  int p = blockIdx.x*256 + threadIdx.x;
  if (p >= NPAIR) return;
  int e = etk[p];
  list[offsets[e] + rank[p]] = p;
}

// ---- grouped gate_up GEMM: BM=128 tokens x BN=64 cols (g and u), BK=64 ----
__global__ __launch_bounds__(256,2) void k_gateup(const unsigned short* __restrict__ xbf,
                                                  const unsigned short* __restrict__ gpack,
                                                  const float* __restrict__ wtk,
                                                  const int* __restrict__ list,
                                                  const int* __restrict__ counts,
                                                  const int* __restrict__ offsets,
                                                  const int* __restrict__ texp,
                                                  const int* __restrict__ tseg,
                                                  const int* __restrict__ hdr,
                                                  unsigned short* __restrict__ hpack) {
  int by = blockIdx.y;
  if (by >= hdr[0]) return;
  int e = texp[by];
  int m0 = tseg[by]*TM;
  int seg0 = offsets[e];
  int cnt = counts[e];
  int rows = min(TM, cnt - m0);
  int fb = blockIdx.x;

  __shared__ __align__(16) unsigned short A_lds[8192];   // 16KB: entry (kkc*128+row)*8
  __shared__ __align__(16) unsigned short Bg_lds[4096];  // 8KB: entry (kkc*64+col)*8
  __shared__ __align__(16) unsigned short Bu_lds[4096];

  int tid = threadIdx.x;
  int wid = tid >> 6, lane = tid & 63;
  int wr = wid >> 1, wc = wid & 1;

  int tok_lo = list[seg0 + min(m0 + lane,      cnt-1)] >> 1;
  int tok_hi = list[seg0 + min(m0 + 64 + lane, cnt-1)] >> 1;

  const unsigned short* gG = gpack + (size_t)(e*64 + fb)     * 16 * 4096;
  const unsigned short* gU = gpack + (size_t)(e*64 + 32 + fb)* 16 * 4096;

  f32x4 accg[4][2] = {};
  f32x4 accu[4][2] = {};

  for (int kb = 0; kb < 16; ++kb) {
    // stage 32 issues of 1KB: waves 0,1 -> A (gather), wave 2 -> Bg, wave 3 -> Bu
    #pragma unroll
    for (int s = 0; s < 8; ++s) {
      int i = wid*8 + s;
      if (i < 16) {
        int kkc = i >> 1, half = i & 1;
        int tok = half ? tok_hi : tok_lo;
        ld16(xbf + (size_t)tok*HID + kb*64 + kkc*8, &A_lds[(kkc*128 + half*64)*8]);
      } else if (i < 24) {
        int j = i - 16;
        ld16(gG + (size_t)kb*4096 + j*512 + lane*8, &Bg_lds[j*512]);
      } else {
        int j = i - 24;
        ld16(gU + (size_t)kb*4096 + j*512 + lane*8, &Bu_lds[j*512]);
      }
    }
    __syncthreads();
    int c4 = lane >> 4, r16 = lane & 15;
    #pragma unroll
    for (int kk = 0; kk < 2; ++kk) {
      bf16x8 a[4], bg[2], bu[2];
      #pragma unroll
      for (int sm = 0; sm < 4; ++sm)
        a[sm] = *(const bf16x8*)&A_lds[((kk*4 + c4)*128 + wr*64 + sm*16 + r16)*8];
      #pragma unroll
      for (int sn = 0; sn < 2; ++sn) {
        bg[sn] = *(const bf16x8*)&Bg_lds[((kk*4 + c4)*64 + wc*32 + sn*16 + r16)*8];
        bu[sn] = *(const bf16x8*)&Bu_lds[((kk*4 + c4)*64 + wc*32 + sn*16 + r16)*8];
      }
      #pragma unroll
      for (int sm = 0; sm < 4; ++sm)
        #pragma unroll
        for (int sn = 0; sn < 2; ++sn) {
          accg[sm][sn] = __builtin_amdgcn_mfma_f32_16x16x32_bf16(a[sm], bg[sn], accg[sm][sn], 0, 0, 0);
          accu[sm][sn] = __builtin_amdgcn_mfma_f32_16x16x32_bf16(a[sm], bu[sn], accu[sm][sn], 0, 0, 0);
        }
    }
    __syncthreads();
  }

  // epilogue: h = silu(g)*u*w -> packed tile (kkc*128+row) in LDS, then linear store
  #pragma unroll
  for (int sm = 0; sm < 4; ++sm) {
    #pragma unroll
    for (int j = 0; j < 4; ++j) {
      int row = wr*64 + sm*16 + (lane>>4)*4 + j;
      float w = (row < rows) ? wtk[list[seg0 + m0 + row]] : 0.f;
      #pragma unroll
      for (int sn = 0; sn < 2; ++sn) {
        int col = wc*32 + sn*16 + (lane & 15);
        float g = accg[sm][sn][j];
        float u = accu[sm][sn][j];
        float hv = g / (1.f + __expf(-g)) * u * w;
        A_lds[((col>>3)*128 + row)*8 + (col&7)] = f2bf(hv);
      }
    }
  }
  __syncthreads();
  unsigned short* dst = hpack + ((size_t)(by*32 + fb))*8192 + tid*32;
  const unsigned short* srcl = &A_lds[tid*32];
  #pragma unroll
  for (int q = 0; q < 4; ++q)
    *(bf16x8*)(dst + q*8) = *(const bf16x8*)(srcl + q*8);
}

// ---- grouped down GEMM: BM=128 slots x BN=64 hid cols, BK=64 over FFN ----
__global__ __launch_bounds__(256,2) void k_down(const unsigned short* __restrict__ hpack,
                                                const unsigned short* __restrict__ dpack,
                                                const int* __restrict__ list,
                                                const int* __restrict__ counts,
                                                const int* __restrict__ offsets,
                                                const int* __restrict__ texp,
                                                const int* __restrict__ tseg,
                                                const int* __restrict__ hdr,
                                                float* __restrict__ out) {
  int by = blockIdx.y;
  if (by >= hdr[0]) return;
  int e = texp[by];
  int m0 = tseg[by]*TM;
  int seg0 = offsets[e];
  int cnt = counts[e];
  int rows = min(TM, cnt - m0);
  int nb = blockIdx.x;

  __shared__ __align__(16) unsigned short A_lds[8192];  // 16KB
  __shared__ __align__(16) unsigned short B_lds[4096];  // 8KB

  int tid = threadIdx.x;
  int wid = tid >> 6, lane = tid & 63;
  int wr = wid >> 1, wc = wid & 1;

  const unsigned short* hA = hpack + (size_t)by * 32 * 8192;
  const unsigned short* gB = dpack + (size_t)(e*16 + nb) * 32 * 4096;

  f32x4 acc[4][2] = {};

  for (int kb = 0; kb < 32; ++kb) {
    #pragma unroll
    for (int s = 0; s < 6; ++s) {
      int i = wid*6 + s;
      if (i < 16) {
        ld16(hA + (size_t)kb*8192 + i*512 + lane*8, &A_lds[i*512]);
      } else {
        int j = i - 16;
        ld16(gB + (size_t)kb*4096 + j*512 + lane*8, &B_lds[j*512]);
      }
    }
    __syncthreads();
    int c4 = lane >> 4, r16 = lane & 15;
    #pragma unroll
    for (int kk = 0; kk < 2; ++kk) {
      bf16x8 a[4], b[2];
      #pragma unroll
      for (int sm = 0; sm < 4; ++sm)
        a[sm] = *(const bf16x8*)&A_lds[((kk*4 + c4)*128 + wr*64 + sm*16 + r16)*8];
      #pragma unroll
      for (int sn = 0; sn < 2; ++sn)
        b[sn] = *(const bf16x8*)&B_lds[((kk*4 + c4)*64 + wc*32 + sn*16 + r16)*8];
      #pragma unroll
      for (int sm = 0; sm < 4; ++sm)
        #pragma unroll
        for (int sn = 0; sn < 2; ++sn)
          acc[sm][sn] = __builtin_amdgcn_mfma_f32_16x16x32_bf16(a[sm], b[sn], acc[sm][sn], 0, 0, 0);
    }
    __syncthreads();
  }

  #pragma unroll
  for (int sm = 0; sm < 4; ++sm) {
    #pragma unroll
    for (int j = 0; j < 4; ++j) {
      int row = wr*64 + sm*16 + (lane>>4)*4 + j;
      if (row < rows) {
        int t = list[seg0 + m0 + row] >> 1;
        #pragma unroll
        for (int sn = 0; sn < 2; ++sn) {
          int col = nb*64 + wc*32 + sn*16 + (lane & 15);
          unsafeAtomicAdd(&out[(size_t)t*HID + col], acc[sm][sn][j]);
        }
      }
    }
  }
}

extern "C" void kernel_launch(void* const* d_in, const int* in_sizes, int n_in,
                              void* d_out, int out_size, void* d_ws, size_t ws_size,
                              hipStream_t stream) {
  const float* x   = (const float*)d_in[0];
  const float* gw  = (const float*)d_in[1];
  const float* gup = (const float*)d_in[2];
  const float* dwn = (const float*)d_in[3];

  float* out = (float*)d_out;
  float* logits = out + (size_t)T_TOKENS*HID;

  char* ws = (char*)d_ws;
  unsigned short* hpack = (unsigned short*)(ws + HPACK_OFF);
  unsigned short* gpack = (unsigned short*)(ws + GPACK_OFF);
  unsigned short* dpack = (unsigned short*)(ws + DPACK_OFF);
  unsigned short* xbf   = (unsigned short*)(ws + XBF_OFF);
  float* wtk   = (float*)(ws + WTK_OFF);
  int* etk     = (int*)(ws + ETK_OFF);
  int* rank    = (int*)(ws + RANK_OFF);
  int* list    = (int*)(ws + LIST_OFF);
  int* counts  = (int*)(ws + CNT_OFF);
  int* offsets = (int*)(ws + OFFS_OFF);
  int* texp    = (int*)(ws + TEXP_OFF);
  int* tseg    = (int*)(ws + TSEG_OFF);
  int* hdr     = (int*)(ws + HDR_OFF);

  hipMemsetAsync(out, 0, (size_t)T_TOKENS*HID*4, stream);
  hipMemsetAsync(counts, 0, 64, stream);

  // routing chain (independent of packing)
  k_logits<<<T_TOKENS/4, 256, 0, stream>>>(x, gw, logits);
  k_route<<<T_TOKENS/256, 256, 0, stream>>>(logits, wtk, etk, rank, counts);
  k_scan<<<1, 64, 0, stream>>>(counts, offsets, texp, tseg, hdr);
  k_scatter<<<NPAIR/256, 256, 0, stream>>>(etk, rank, offsets, list);

  // conversions / packing
  k_xbf<<<(T_TOKENS*HID/8)/256, 256, 0, stream>>>(x, xbf);
  {
    dim3 g(16, 64, NEXP);   // kb, nb, e   : gup  [E][4096][1024]
    k_pack<<<g, 256, 0, stream>>>(gup, gpack, 64, 16, HID);
  }
  {
    dim3 g(32, 16, NEXP);   // kb, nb, e   : down [E][1024][2048]
    k_pack<<<g, 256, 0, stream>>>(dwn, dpack, 16, 32, FFN);
  }

  dim3 g3(FFN/64, MAXTILES);
  k_gateup<<<g3, 256, 0, stream>>>(xbf, gpack, wtk, list, counts, offsets, texp, tseg, hdr, hpack);

  dim3 g4(HID/64, MAXTILES);
  k_down<<<g4, 256, 0, stream>>>(hpack, dpack, list, counts, offsets, texp, tseg, hdr, out);
}